// Round 4
// baseline (518.302 us; speedup 1.0000x reference)
//
#include <hip/hip_runtime.h>
#include <hip/hip_bf16.h>
#include <math.h>

#define M_TOK 16384
#define N_EXP 256
#define K_DIM 7168
#define BM 64
#define BK 32
#define KSTEPS (K_DIM / BK)  /* 224 */
#define WTILE 49152          /* bytes per k-step W image: 16KB hi + 16KB mid + 16KB lo */
#define TOPK 8

typedef __attribute__((ext_vector_type(8))) short short8;
typedef __attribute__((ext_vector_type(4))) float f32x4;

__device__ __forceinline__ unsigned short f2bf(float f) {
  unsigned int u = __builtin_bit_cast(unsigned int, f);
  unsigned int r = (u + 0x7FFFu + ((u >> 16) & 1u)) >> 16;  // RNE
  return (unsigned short)r;
}
__device__ __forceinline__ float bf2f(unsigned short h) {
  unsigned int u = ((unsigned int)h) << 16;
  return __builtin_bit_cast(float, u);
}
// 3-way split: x = hi + mid + lo with residual <= 2^-27 |x|
__device__ __forceinline__ void cvt8_3(const float* v, short8& h, short8& m, short8& l) {
#pragma unroll
  for (int i = 0; i < 8; ++i) {
    unsigned short a = f2bf(v[i]);
    float r1 = v[i] - bf2f(a);       // exact in fp32
    unsigned short b = f2bf(r1);
    float r2 = r1 - bf2f(b);         // exact in fp32
    unsigned short c = f2bf(r2);
    h[i] = (short)a;
    m[i] = (short)b;
    l[i] = (short)c;
  }
}

// monotone fp32 -> u32 key (no NaN inputs), pack with inverted index for
// lax.top_k tie-break (descending value, lowest index first on exact ties)
__device__ __forceinline__ unsigned long long pack_ci(float key, int idx) {
  unsigned int u = __builtin_bit_cast(unsigned int, key);
  u = (u & 0x80000000u) ? ~u : (u | 0x80000000u);
  return ((unsigned long long)u << 32) | (unsigned)(255 - idx);
}
__device__ __forceinline__ unsigned long long shflx64(unsigned long long v, int off) {
  int lo = __shfl_xor((int)(unsigned)(v & 0xffffffffull), off);
  int hi = __shfl_xor((int)(unsigned)(v >> 32), off);
  return ((unsigned long long)(unsigned)hi << 32) | (unsigned)lo;
}

// Convert gate_weight fp32 [256][7168] into per-kstep swizzled LDS images in ws.
// Image t (48KB): hi plane [256][32]bf16 at +0, mid at +16384, lo at +32768.
// byte col within a row = (kc*16) ^ ((row&6)<<3)  -- matches frag-read swizzle.
__global__ void prep_w_kernel(const float* __restrict__ W, unsigned char* __restrict__ ws) {
  int t = blockIdx.x;    // kstep
  int e = threadIdx.x;   // expert row
  const float* src = W + (size_t)e * K_DIM + t * BK;
  unsigned char* dst = ws + (size_t)t * WTILE;
#pragma unroll
  for (int kc = 0; kc < 4; ++kc) {
    float v[8];
    float4 a = ((const float4*)src)[kc * 2];
    float4 b = ((const float4*)src)[kc * 2 + 1];
    v[0] = a.x; v[1] = a.y; v[2] = a.z; v[3] = a.w;
    v[4] = b.x; v[5] = b.y; v[6] = b.z; v[7] = b.w;
    short8 h, m, l;
    cvt8_3(v, h, m, l);
    int col = (kc * 16) ^ ((e & 6) << 3);
    *(short8*)(dst + e * 64 + col) = h;
    *(short8*)(dst + 16384 + e * 64 + col) = m;
    *(short8*)(dst + 32768 + e * 64 + col) = l;
  }
}

template <bool USE_WS>
__global__ __launch_bounds__(256, 1) void gate_kernel(
    const float* __restrict__ X,
    const float* __restrict__ Wg,
    const unsigned char* __restrict__ ws,
    const float* __restrict__ bias,
    float* __restrict__ out) {
  // LDS: A bufs [2][12KB] at 0 (3 planes x 4KB); B bufs [2][48KB] at 24576
  // (3 planes x 16KB). Epilogue reuses bytes 0..66559 as scores [64][260] f32.
  __shared__ unsigned char smem[122880] __attribute__((aligned(16)));

  const int tid = threadIdx.x;
  const int lane = tid & 63;
  const int wid = tid >> 6;
  const int lr = lane & 15;
  const int lg = lane >> 4;
  const int m0 = blockIdx.x * BM;

  // Frag byte offsets (constant over K): lane l reads row (base + l&15),
  // k-chunk (l>>4)*8 bf16 = 16B, with XOR swizzle for bank-conflict freedom.
  int aOff[4], bOff[4];
#pragma unroll
  for (int m = 0; m < 4; ++m) {
    int r = m * 16 + lr;
    aOff[m] = r * 64 + ((lg * 16) ^ ((r & 6) << 3));
  }
#pragma unroll
  for (int n = 0; n < 4; ++n) {
    int e = wid * 64 + n * 16 + lr;
    bOff[n] = e * 64 + ((lg * 16) ^ ((e & 6) << 3));
  }

  // X staging: thread -> (row, k-chunk of 8 floats)
  const int xr = tid >> 2;
  const int xkc = tid & 3;
  const float* xsrc = X + (size_t)(m0 + xr) * K_DIM + xkc * 8;
  const int xcol = (xkc * 16) ^ ((xr & 6) << 3);

  float xv[8];
  auto load_x = [&](int t) {
    float4 a = *(const float4*)(xsrc + (size_t)t * BK);
    float4 b = *(const float4*)(xsrc + (size_t)t * BK + 4);
    xv[0] = a.x; xv[1] = a.y; xv[2] = a.z; xv[3] = a.w;
    xv[4] = b.x; xv[5] = b.y; xv[6] = b.z; xv[7] = b.w;
  };
  auto write_x = [&](int b) {
    short8 h, m, l;
    cvt8_3(xv, h, m, l);
    unsigned char* Ab = smem + b * 12288;
    *(short8*)(Ab + xr * 64 + xcol) = h;
    *(short8*)(Ab + 4096 + xr * 64 + xcol) = m;
    *(short8*)(Ab + 8192 + xr * 64 + xcol) = l;
  };
  auto stage_w = [&](int t, int b) {
    unsigned char* Bb = smem + 24576 + b * 49152;
    if constexpr (USE_WS) {
      const unsigned char* src = ws + (size_t)t * WTILE;
#pragma unroll
      for (int i = 0; i < 12; ++i) {
        int off = i * 4096 + wid * 1024 + lane * 16;
        __builtin_amdgcn_global_load_lds(
            (const __attribute__((address_space(1))) void*)(src + off),
            (__attribute__((address_space(3))) void*)(Bb + off), 16, 0, 0);
      }
    } else {
      const float* src = Wg + (size_t)tid * K_DIM + (size_t)t * BK;
#pragma unroll
      for (int kc = 0; kc < 4; ++kc) {
        float v[8];
        float4 a = ((const float4*)src)[kc * 2];
        float4 bq = ((const float4*)src)[kc * 2 + 1];
        v[0] = a.x; v[1] = a.y; v[2] = a.z; v[3] = a.w;
        v[4] = bq.x; v[5] = bq.y; v[6] = bq.z; v[7] = bq.w;
        short8 h, m, l;
        cvt8_3(v, h, m, l);
        int col = (kc * 16) ^ ((tid & 6) << 3);
        *(short8*)(Bb + tid * 64 + col) = h;
        *(short8*)(Bb + 16384 + tid * 64 + col) = m;
        *(short8*)(Bb + 32768 + tid * 64 + col) = l;
      }
    }
  };

  f32x4 acc[4][4];   // xh*wh (main term)
  f32x4 accc[4][4];  // correction terms (each <= 2^-9 of main)
#pragma unroll
  for (int m = 0; m < 4; ++m)
#pragma unroll
    for (int n = 0; n < 4; ++n) {
      acc[m][n] = (f32x4){0.f, 0.f, 0.f, 0.f};
      accc[m][n] = (f32x4){0.f, 0.f, 0.f, 0.f};
    }

  // prologue: stage tile 0
  stage_w(0, 0);
  load_x(0);
  write_x(0);
  __syncthreads();

  for (int t = 0; t < KSTEPS; ++t) {
    int cur = t & 1, nxt = cur ^ 1;
    if (t + 1 < KSTEPS) {
      stage_w(t + 1, nxt);  // async W prefetch into other buffer
      load_x(t + 1);        // X prefetch into regs
    }
    const unsigned char* Ab = smem + cur * 12288;
    const unsigned char* Bb = smem + 24576 + cur * 49152;
    short8 xh[4], xm_[4], xl_[4], wh[4], wm_[4], wl_[4];
#pragma unroll
    for (int m = 0; m < 4; ++m) {
      xh[m] = *(const short8*)(Ab + aOff[m]);
      xm_[m] = *(const short8*)(Ab + 4096 + aOff[m]);
      xl_[m] = *(const short8*)(Ab + 8192 + aOff[m]);
    }
#pragma unroll
    for (int n = 0; n < 4; ++n) {
      wh[n] = *(const short8*)(Bb + bOff[n]);
      wm_[n] = *(const short8*)(Bb + 16384 + bOff[n]);
      wl_[n] = *(const short8*)(Bb + 32768 + bOff[n]);
    }
#pragma unroll
    for (int m = 0; m < 4; ++m)
#pragma unroll
      for (int n = 0; n < 4; ++n) {
        acc[m][n] = __builtin_amdgcn_mfma_f32_16x16x32_bf16(xh[m], wh[n], acc[m][n], 0, 0, 0);
        f32x4 c = accc[m][n];
        c = __builtin_amdgcn_mfma_f32_16x16x32_bf16(xh[m], wm_[n], c, 0, 0, 0);
        c = __builtin_amdgcn_mfma_f32_16x16x32_bf16(xm_[m], wh[n], c, 0, 0, 0);
        c = __builtin_amdgcn_mfma_f32_16x16x32_bf16(xh[m], wl_[n], c, 0, 0, 0);
        c = __builtin_amdgcn_mfma_f32_16x16x32_bf16(xm_[m], wm_[n], c, 0, 0, 0);
        c = __builtin_amdgcn_mfma_f32_16x16x32_bf16(xl_[m], wh[n], c, 0, 0, 0);
        accc[m][n] = c;
      }
    if (t + 1 < KSTEPS) write_x(nxt);
    __syncthreads();
  }

  // ---- epilogue: sigmoid -> LDS scores [64][260] (padded vs bank conflicts)
  float* sc = (float*)smem;
#pragma unroll
  for (int m = 0; m < 4; ++m)
#pragma unroll
    for (int n = 0; n < 4; ++n)
#pragma unroll
      for (int r = 0; r < 4; ++r) {
        int row = m * 16 + lg * 4 + r;
        int col = wid * 64 + n * 16 + lr;
        float v = acc[m][n][r] + accc[m][n][r];
        sc[row * 260 + col] = 1.0f / (1.0f + expf(-v));
      }
  __syncthreads();

  // ---- fused top-8: exact lax.top_k semantics via packed (key, 255-idx) u64
  const float bb0 = bias[lane];
  const float bb1 = bias[lane + 64];
  const float bb2 = bias[lane + 128];
  const float bb3 = bias[lane + 192];
  const size_t TOT = (size_t)M_TOK * TOPK;

  for (int i = 0; i < 16; ++i) {
    int row = wid * 16 + i;
    float s0 = sc[row * 260 + lane];
    float s1 = sc[row * 260 + lane + 64];
    float s2 = sc[row * 260 + lane + 128];
    float s3 = sc[row * 260 + lane + 192];
    unsigned long long c0 = pack_ci(s0 + bb0, lane);
    unsigned long long c1 = pack_ci(s1 + bb1, lane + 64);
    unsigned long long c2 = pack_ci(s2 + bb2, lane + 128);
    unsigned long long c3 = pack_ci(s3 + bb3, lane + 192);
    float ssum = 0.f, my_s = 0.f;
    int my_idx = 0;
#pragma unroll
    for (int p = 0; p < TOPK; ++p) {
      unsigned long long b01 = c0 > c1 ? c0 : c1;
      unsigned long long b23 = c2 > c3 ? c2 : c3;
      unsigned long long best = b01 > b23 ? b01 : b23;
#pragma unroll
      for (int off = 1; off < 64; off <<= 1) {
        unsigned long long o = shflx64(best, off);
        if (o > best) best = o;
      }
      int idxw = 255 - (int)(best & 0xffull);
      int lw = idxw & 63;
      int jw = idxw >> 6;  // wave-uniform
      float sel = jw == 0 ? s0 : jw == 1 ? s1 : jw == 2 ? s2 : s3;
      float sw = __shfl(sel, lw);
      ssum += sw;
      if (lane == p) { my_idx = idxw; my_s = sw; }
      if (lane == lw) {
        if (jw == 0) c0 = 0ull;
        else if (jw == 1) c1 = 0ull;
        else if (jw == 2) c2 = 0ull;
        else c3 = 0ull;
      }
    }
    if (lane < TOPK) {
      size_t rg = (size_t)(m0 + row);
      out[rg * TOPK + lane] = (float)my_idx;                          // indices
      out[TOT + rg * TOPK + lane] = my_s * (2.5f / (ssum + 1e-20f));  // weights
    }
  }
}

extern "C" void kernel_launch(void* const* d_in, const int* in_sizes, int n_in,
                              void* d_out, int out_size, void* d_ws, size_t ws_size,
                              hipStream_t stream) {
  const float* X = (const float*)d_in[0];
  const float* W = (const float*)d_in[1];
  const float* bias = (const float*)d_in[2];
  float* out = (float*)d_out;

  const size_t wneed = (size_t)KSTEPS * WTILE;  // 11.0 MB
  if (d_ws != nullptr && ws_size >= wneed) {
    prep_w_kernel<<<KSTEPS, 256, 0, stream>>>(W, (unsigned char*)d_ws);
    gate_kernel<true><<<M_TOK / BM, 256, 0, stream>>>(
        X, W, (const unsigned char*)d_ws, bias, out);
  } else {
    gate_kernel<false><<<M_TOK / BM, 256, 0, stream>>>(X, W, nullptr, bias, out);
  }
}

// Round 5
// 309.057 us; speedup vs baseline: 1.6770x; 1.6770x over previous
//
#include <hip/hip_runtime.h>
#include <hip/hip_bf16.h>
#include <math.h>

#define M_TOK 16384
#define N_EXP 256
#define K_DIM 7168
#define BM 64
#define BK 32
#define KSTEPS (K_DIM / BK)  /* 224 */
#define WTILE 32768          /* bytes per k-step W image: 16KB hi + 16KB lo (fp16) */
#define TOPK 8
#define SX 4096.0f           /* x prescale (exact pow2) */
#define SW 16384.0f          /* w prescale (exact pow2) */
#define DESCALE 1.4901161193847656e-08f /* 2^-26 = 1/(SX*SW) */

typedef __attribute__((ext_vector_type(8))) _Float16 half8;
typedef __attribute__((ext_vector_type(4))) _Float16 half4;
typedef __attribute__((ext_vector_type(4))) float f32x4;

// 2-way fp16 split of prescaled fp32: v = h + l + r, |r| <= 2^-24 |v|.
// (v - (float)h is exact in fp32 by Dekker alignment.)
__device__ __forceinline__ void cvt8_2(const float* v, half8& h, half8& l) {
#pragma unroll
  for (int i = 0; i < 8; ++i) {
    _Float16 a = (_Float16)v[i];
    float r = v[i] - (float)a;
    h[i] = a;
    l[i] = (_Float16)r;
  }
}
__device__ __forceinline__ void cvt4_2(const float* v, half4& h, half4& l) {
#pragma unroll
  for (int i = 0; i < 4; ++i) {
    _Float16 a = (_Float16)v[i];
    float r = v[i] - (float)a;
    h[i] = a;
    l[i] = (_Float16)r;
  }
}

// monotone fp32 -> u32 key (no NaN inputs), pack with inverted index for
// lax.top_k tie-break (descending value, lowest index first on exact ties)
__device__ __forceinline__ unsigned long long pack_ci(float key, int idx) {
  unsigned int u = __builtin_bit_cast(unsigned int, key);
  u = (u & 0x80000000u) ? ~u : (u | 0x80000000u);
  return ((unsigned long long)u << 32) | (unsigned)(255 - idx);
}
__device__ __forceinline__ unsigned long long shflx64(unsigned long long v, int off) {
  int lo = __shfl_xor((int)(unsigned)(v & 0xffffffffull), off);
  int hi = __shfl_xor((int)(unsigned)(v >> 32), off);
  return ((unsigned long long)(unsigned)hi << 32) | (unsigned)lo;
}

// gate_weight fp32 [256][7168] -> per-kstep swizzled fp16 LDS images in ws.
// Image t (32KB): hi plane [256 rows][64B] at +0, lo plane at +16384.
// byte col of 16B granule kc: (kc*16) ^ ((row&6)<<3) -- matches frag reads.
__global__ void prep_w_kernel(const float* __restrict__ W, unsigned char* __restrict__ ws) {
  int t = blockIdx.x;    // kstep
  int e = threadIdx.x;   // expert row
  const float* src = W + (size_t)e * K_DIM + t * BK;
  unsigned char* dst = ws + (size_t)t * WTILE;
#pragma unroll
  for (int kc = 0; kc < 4; ++kc) {
    float v[8];
    float4 a = ((const float4*)src)[kc * 2];
    float4 b = ((const float4*)src)[kc * 2 + 1];
    v[0] = a.x * SW; v[1] = a.y * SW; v[2] = a.z * SW; v[3] = a.w * SW;
    v[4] = b.x * SW; v[5] = b.y * SW; v[6] = b.z * SW; v[7] = b.w * SW;
    half8 h, l;
    cvt8_2(v, h, l);
    int col = (kc * 16) ^ ((e & 6) << 3);
    *(half8*)(dst + e * 64 + col) = h;
    *(half8*)(dst + 16384 + e * 64 + col) = l;
  }
}

template <bool USE_WS>
__global__ __launch_bounds__(512, 2) void gate_kernel(
    const float* __restrict__ X,
    const float* __restrict__ Wg,
    const unsigned char* __restrict__ ws,
    const float* __restrict__ bias,
    float* __restrict__ out) {
  // LDS 80KB: A bufs [2][8KB] at 0 (hi 4KB, lo 4KB); B bufs [2][32KB] at
  // 16384 (hi 16KB, lo 16KB). Epilogue reuses 0..66559 as scores [64][260].
  __shared__ unsigned char smem[81920] __attribute__((aligned(16)));

  const int tid = threadIdx.x;
  const int lane = tid & 63;
  const int wid = tid >> 6;   // 0..7
  const int wm = wid >> 2;    // 0..1  (M group: rows wm*32..+32)
  const int wn = wid & 3;     // 0..3  (N group: experts wn*64..+64)
  const int lr = lane & 15;
  const int lg = lane >> 4;
  const int m0 = blockIdx.x * BM;

  // Frag byte offsets: lane reads row base+lr, 16B k-chunk lg, XOR-swizzled.
  int aOff[2], bOff[4];
#pragma unroll
  for (int m = 0; m < 2; ++m) {
    int r = wm * 32 + m * 16 + lr;
    aOff[m] = r * 64 + ((lg * 16) ^ ((r & 6) << 3));
  }
#pragma unroll
  for (int n = 0; n < 4; ++n) {
    int e = wn * 64 + n * 16 + lr;
    bOff[n] = e * 64 + ((lg * 16) ^ ((e & 6) << 3));
  }

  // X staging: 512 threads cover 64 rows x 8 chunks of 4 floats
  const int xr = tid >> 3;
  const int xkc = tid & 7;
  const float* xsrc = X + (size_t)(m0 + xr) * K_DIM + xkc * 4;
  const int xcol = (xkc * 8) ^ ((xr & 6) << 3);

  float4 xv;
  auto load_x = [&](int t) { xv = *(const float4*)(xsrc + (size_t)t * BK); };
  auto write_x = [&](int b) {
    float v[4] = {xv.x * SX, xv.y * SX, xv.z * SX, xv.w * SX};
    half4 h, l;
    cvt4_2(v, h, l);
    unsigned char* Ab = smem + b * 8192;
    *(half4*)(Ab + xr * 64 + xcol) = h;
    *(half4*)(Ab + 4096 + xr * 64 + xcol) = l;
  };
  auto stage_w = [&](int t, int b) {
    unsigned char* Bb = smem + 16384 + b * 32768;
    if constexpr (USE_WS) {
      const unsigned char* src = ws + (size_t)t * WTILE;
#pragma unroll
      for (int i = 0; i < 4; ++i) {
        int off = i * 8192 + tid * 16;
        __builtin_amdgcn_global_load_lds(
            (const __attribute__((address_space(1))) void*)(src + off),
            (__attribute__((address_space(3))) void*)(Bb + off), 16, 0, 0);
      }
    } else {
      // fallback: convert from Wg directly; thread -> (row, 2 granules)
      int row = tid >> 1;
      int g0 = (tid & 1) * 2;
      const float* src = Wg + (size_t)row * K_DIM + (size_t)t * BK + g0 * 8;
#pragma unroll
      for (int g = 0; g < 2; ++g) {
        float v[8];
        float4 a = ((const float4*)src)[g * 2];
        float4 bq = ((const float4*)src)[g * 2 + 1];
        v[0] = a.x * SW; v[1] = a.y * SW; v[2] = a.z * SW; v[3] = a.w * SW;
        v[4] = bq.x * SW; v[5] = bq.y * SW; v[6] = bq.z * SW; v[7] = bq.w * SW;
        half8 h, l;
        cvt8_2(v, h, l);
        int col = ((g0 + g) * 16) ^ ((row & 6) << 3);
        *(half8*)(Bb + row * 64 + col) = h;
        *(half8*)(Bb + 16384 + row * 64 + col) = l;
      }
    }
  };

  f32x4 acc[2][4];   // xh*wh (main term)
  f32x4 accc[2][4];  // correction terms xh*wl + xl*wh (<= 2^-12 of main)
#pragma unroll
  for (int m = 0; m < 2; ++m)
#pragma unroll
    for (int n = 0; n < 4; ++n) {
      acc[m][n] = (f32x4){0.f, 0.f, 0.f, 0.f};
      accc[m][n] = (f32x4){0.f, 0.f, 0.f, 0.f};
    }

  // prologue
  stage_w(0, 0);
  load_x(0);
  write_x(0);
  __syncthreads();

  for (int t = 0; t < KSTEPS; ++t) {
    int cur = t & 1, nxt = cur ^ 1;
    if (t + 1 < KSTEPS) {
      stage_w(t + 1, nxt);  // async W prefetch into other buffer
      load_x(t + 1);        // X prefetch into regs
    }
    const unsigned char* Ab = smem + cur * 8192;
    const unsigned char* Bb = smem + 16384 + cur * 32768;
    half8 xh[2], xl[2], wh[4], wl[4];
#pragma unroll
    for (int m = 0; m < 2; ++m) {
      xh[m] = *(const half8*)(Ab + aOff[m]);
      xl[m] = *(const half8*)(Ab + 4096 + aOff[m]);
    }
#pragma unroll
    for (int n = 0; n < 4; ++n) {
      wh[n] = *(const half8*)(Bb + bOff[n]);
      wl[n] = *(const half8*)(Bb + 16384 + bOff[n]);
    }
#pragma unroll
    for (int m = 0; m < 2; ++m)
#pragma unroll
      for (int n = 0; n < 4; ++n) {
        acc[m][n] = __builtin_amdgcn_mfma_f32_16x16x32_f16(xh[m], wh[n], acc[m][n], 0, 0, 0);
        f32x4 c = accc[m][n];
        c = __builtin_amdgcn_mfma_f32_16x16x32_f16(xh[m], wl[n], c, 0, 0, 0);
        c = __builtin_amdgcn_mfma_f32_16x16x32_f16(xl[m], wh[n], c, 0, 0, 0);
        accc[m][n] = c;
      }
    if (t + 1 < KSTEPS) write_x(nxt);
    __syncthreads();
  }

  // ---- epilogue: sigmoid -> LDS scores [64][260] f32 (padded)
  float* sc = (float*)smem;
#pragma unroll
  for (int m = 0; m < 2; ++m)
#pragma unroll
    for (int n = 0; n < 4; ++n)
#pragma unroll
      for (int r = 0; r < 4; ++r) {
        int row = wm * 32 + m * 16 + lg * 4 + r;
        int col = wn * 64 + n * 16 + lr;
        float v = (acc[m][n][r] + accc[m][n][r]) * DESCALE;
        sc[row * 260 + col] = 1.0f / (1.0f + expf(-v));
      }
  __syncthreads();

  // ---- fused top-8: exact lax.top_k semantics via packed (key, 255-idx) u64
  const float bb0 = bias[lane];
  const float bb1 = bias[lane + 64];
  const float bb2 = bias[lane + 128];
  const float bb3 = bias[lane + 192];
  const size_t TOT = (size_t)M_TOK * TOPK;

  for (int i = 0; i < 8; ++i) {
    int row = wid * 8 + i;
    float s0 = sc[row * 260 + lane];
    float s1 = sc[row * 260 + lane + 64];
    float s2 = sc[row * 260 + lane + 128];
    float s3 = sc[row * 260 + lane + 192];
    unsigned long long c0 = pack_ci(s0 + bb0, lane);
    unsigned long long c1 = pack_ci(s1 + bb1, lane + 64);
    unsigned long long c2 = pack_ci(s2 + bb2, lane + 128);
    unsigned long long c3 = pack_ci(s3 + bb3, lane + 192);
    float ssum = 0.f, my_s = 0.f;
    int my_idx = 0;
#pragma unroll
    for (int p = 0; p < TOPK; ++p) {
      unsigned long long b01 = c0 > c1 ? c0 : c1;
      unsigned long long b23 = c2 > c3 ? c2 : c3;
      unsigned long long best = b01 > b23 ? b01 : b23;
#pragma unroll
      for (int off = 1; off < 64; off <<= 1) {
        unsigned long long o = shflx64(best, off);
        if (o > best) best = o;
      }
      int idxw = 255 - (int)(best & 0xffull);
      int lw = idxw & 63;
      int jw = idxw >> 6;  // wave-uniform
      float sel = jw == 0 ? s0 : jw == 1 ? s1 : jw == 2 ? s2 : s3;
      float sw = __shfl(sel, lw);
      ssum += sw;
      if (lane == p) { my_idx = idxw; my_s = sw; }
      if (lane == lw) {
        if (jw == 0) c0 = 0ull;
        else if (jw == 1) c1 = 0ull;
        else if (jw == 2) c2 = 0ull;
        else c3 = 0ull;
      }
    }
    if (lane < TOPK) {
      size_t rg = (size_t)(m0 + row);
      out[rg * TOPK + lane] = (float)my_idx;                          // indices
      out[TOT + rg * TOPK + lane] = my_s * (2.5f / (ssum + 1e-20f));  // weights
    }
  }
}

extern "C" void kernel_launch(void* const* d_in, const int* in_sizes, int n_in,
                              void* d_out, int out_size, void* d_ws, size_t ws_size,
                              hipStream_t stream) {
  const float* X = (const float*)d_in[0];
  const float* W = (const float*)d_in[1];
  const float* bias = (const float*)d_in[2];
  float* out = (float*)d_out;

  const size_t wneed = (size_t)KSTEPS * WTILE;  // 7.34 MB
  if (d_ws != nullptr && ws_size >= wneed) {
    prep_w_kernel<<<KSTEPS, 256, 0, stream>>>(W, (unsigned char*)d_ws);
    gate_kernel<true><<<M_TOK / BM, 512, 0, stream>>>(
        X, W, (const unsigned char*)d_ws, bias, out);
  } else {
    gate_kernel<false><<<M_TOK / BM, 512, 0, stream>>>(X, W, nullptr, bias, out);
  }
}

// Round 6
// 289.374 us; speedup vs baseline: 1.7911x; 1.0680x over previous
//
#include <hip/hip_runtime.h>
#include <hip/hip_bf16.h>
#include <math.h>

#define M_TOK 16384
#define N_EXP 256
#define K_DIM 7168
#define BM 64
#define BK 32
#define KSTEPS (K_DIM / BK)  /* 224 */
#define WTILE 32768          /* bytes per k-step W image: 16KB hi + 16KB lo (fp16) */
#define TOPK 8
#define SX 4096.0f           /* x prescale (exact pow2) */
#define SW 16384.0f          /* w prescale (exact pow2) */
#define DESCALE 1.4901161193847656e-08f /* 2^-26 = 1/(SX*SW) */

typedef __attribute__((ext_vector_type(8))) _Float16 half8;
typedef __attribute__((ext_vector_type(4))) _Float16 half4;
typedef __attribute__((ext_vector_type(4))) float f32x4;

// 2-way fp16 split of prescaled fp32: v = h + l + r, |r| <= 2^-24 |v|.
__device__ __forceinline__ void cvt8_2(const float* v, half8& h, half8& l) {
#pragma unroll
  for (int i = 0; i < 8; ++i) {
    _Float16 a = (_Float16)v[i];
    float r = v[i] - (float)a;
    h[i] = a;
    l[i] = (_Float16)r;
  }
}
__device__ __forceinline__ void cvt4_2(const float* v, half4& h, half4& l) {
#pragma unroll
  for (int i = 0; i < 4; ++i) {
    _Float16 a = (_Float16)v[i];
    float r = v[i] - (float)a;
    h[i] = a;
    l[i] = (_Float16)r;
  }
}

// monotone fp32 -> u32 key (no NaN inputs), pack with inverted index for
// lax.top_k tie-break (descending value, lowest index first on exact ties)
__device__ __forceinline__ unsigned long long pack_ci(float key, int idx) {
  unsigned int u = __builtin_bit_cast(unsigned int, key);
  u = (u & 0x80000000u) ? ~u : (u | 0x80000000u);
  return ((unsigned long long)u << 32) | (unsigned)(255 - idx);
}
__device__ __forceinline__ unsigned long long shflx64(unsigned long long v, int off) {
  int lo = __shfl_xor((int)(unsigned)(v & 0xffffffffull), off);
  int hi = __shfl_xor((int)(unsigned)(v >> 32), off);
  return ((unsigned long long)(unsigned)hi << 32) | (unsigned)lo;
}

// gate_weight fp32 [256][7168] -> per-kstep swizzled fp16 LDS images in ws.
// Image t (32KB): hi plane [256 rows][64B] at +0, lo plane at +16384.
// byte col of 16B granule kc: (kc*16) ^ ((row&6)<<3) -- matches frag reads.
__global__ void prep_w_kernel(const float* __restrict__ W, unsigned char* __restrict__ ws) {
  int t = blockIdx.x;    // kstep
  int e = threadIdx.x;   // expert row
  const float* src = W + (size_t)e * K_DIM + t * BK;
  unsigned char* dst = ws + (size_t)t * WTILE;
#pragma unroll
  for (int kc = 0; kc < 4; ++kc) {
    float v[8];
    float4 a = ((const float4*)src)[kc * 2];
    float4 b = ((const float4*)src)[kc * 2 + 1];
    v[0] = a.x * SW; v[1] = a.y * SW; v[2] = a.z * SW; v[3] = a.w * SW;
    v[4] = b.x * SW; v[5] = b.y * SW; v[6] = b.z * SW; v[7] = b.w * SW;
    half8 h, l;
    cvt8_2(v, h, l);
    int col = (kc * 16) ^ ((e & 6) << 3);
    *(half8*)(dst + e * 64 + col) = h;
    *(half8*)(dst + 16384 + e * 64 + col) = l;
  }
}

template <bool USE_WS>
__global__ __launch_bounds__(512, 2) void gate_kernel(
    const float* __restrict__ X,
    const float* __restrict__ Wg,
    const unsigned char* __restrict__ ws,
    const float* __restrict__ bias,
    float* __restrict__ out) {
  // LDS 80KB: A bufs [2][8KB] at 0 (hi 4KB, lo 4KB); B bufs [2][32KB] at
  // 16384 (hi 16KB, lo 16KB). Epilogue reuses 0..66559 as scores [64][260].
  __shared__ unsigned char smem[81920] __attribute__((aligned(16)));

  const int tid = threadIdx.x;
  const int lane = tid & 63;
  const int wid = tid >> 6;   // 0..7
  const int wm = wid >> 2;    // 0..1  (M group: rows wm*32..+32)
  const int wn = wid & 3;     // 0..3  (N group: experts wn*64..+64)
  const int lr = lane & 15;
  const int lg = lane >> 4;
  const int m0 = blockIdx.x * BM;

  // Frag byte offsets: lane reads row base+lr, 16B k-chunk lg, XOR-swizzled.
  int aOff[2], bOff[4];
#pragma unroll
  for (int m = 0; m < 2; ++m) {
    int r = wm * 32 + m * 16 + lr;
    aOff[m] = r * 64 + ((lg * 16) ^ ((r & 6) << 3));
  }
#pragma unroll
  for (int n = 0; n < 4; ++n) {
    int e = wn * 64 + n * 16 + lr;
    bOff[n] = e * 64 + ((lg * 16) ^ ((e & 6) << 3));
  }

  // X staging: 512 threads cover 64 rows x 8 chunks of 4 floats
  const int xr = tid >> 3;
  const int xkc = tid & 7;
  const float* xsrc = X + (size_t)(m0 + xr) * K_DIM + xkc * 4;
  const int xcol = (xkc * 8) ^ ((xr & 6) << 3);

  auto load_x = [&](int t, float4& dst) {
    dst = *(const float4*)(xsrc + (size_t)t * BK);
  };
  auto write_x = [&](int b, const float4& xv) {
    float v[4] = {xv.x * SX, xv.y * SX, xv.z * SX, xv.w * SX};
    half4 h, l;
    cvt4_2(v, h, l);
    unsigned char* Ab = smem + b * 8192;
    *(half4*)(Ab + xr * 64 + xcol) = h;
    *(half4*)(Ab + 4096 + xr * 64 + xcol) = l;
  };
  auto stage_w = [&](int t, int b) {
    unsigned char* Bb = smem + 16384 + b * 32768;
    if constexpr (USE_WS) {
      const unsigned char* src = ws + (size_t)t * WTILE;
#pragma unroll
      for (int i = 0; i < 4; ++i) {
        int off = i * 8192 + tid * 16;
        __builtin_amdgcn_global_load_lds(
            (const __attribute__((address_space(1))) void*)(src + off),
            (__attribute__((address_space(3))) void*)(Bb + off), 16, 0, 0);
      }
    } else {
      // fallback: convert from Wg directly; thread -> (row, 2 granules)
      int row = tid >> 1;
      int g0 = (tid & 1) * 2;
      const float* src = Wg + (size_t)row * K_DIM + (size_t)t * BK + g0 * 8;
#pragma unroll
      for (int g = 0; g < 2; ++g) {
        float v[8];
        float4 a = ((const float4*)src)[g * 2];
        float4 bq = ((const float4*)src)[g * 2 + 1];
        v[0] = a.x * SW; v[1] = a.y * SW; v[2] = a.z * SW; v[3] = a.w * SW;
        v[4] = bq.x * SW; v[5] = bq.y * SW; v[6] = bq.z * SW; v[7] = bq.w * SW;
        half8 h, l;
        cvt8_2(v, h, l);
        int col = ((g0 + g) * 16) ^ ((row & 6) << 3);
        *(half8*)(Bb + row * 64 + col) = h;
        *(half8*)(Bb + 16384 + row * 64 + col) = l;
      }
    }
  };

  f32x4 acc[2][4];   // xh*wh (main term)
  f32x4 accc[2][4];  // correction terms xh*wl + xl*wh (<= 2^-12 of main)
#pragma unroll
  for (int m = 0; m < 2; ++m)
#pragma unroll
    for (int n = 0; n < 4; ++n) {
      acc[m][n] = (f32x4){0.f, 0.f, 0.f, 0.f};
      accc[m][n] = (f32x4){0.f, 0.f, 0.f, 0.f};
    }

  // One pipeline stage. Consumes xcons (=X(t+1)), loads X(t+2) into xload.
  // Schedule (T3/T4): stage W first, then X load, counted vmcnt(1) before
  // raw barrier so W(t+1) is drained per-wave pre-barrier while X(t+2)
  // stays in flight across it.
  auto body = [&](int t, float4& xload, const float4& xcons) {
    const int cur = t & 1, nxt = cur ^ 1;
    if (t + 1 < KSTEPS) stage_w(t + 1, nxt);   // 4x global_load_lds
    if (t + 2 < KSTEPS) load_x(t + 2, xload);  // 1x global float4 -> reg

    const unsigned char* Ab = smem + cur * 8192;
    const unsigned char* Bb = smem + 16384 + cur * 32768;
    half8 xh[2], xl[2], wh[4], wl[4];
#pragma unroll
    for (int m = 0; m < 2; ++m) {
      xh[m] = *(const half8*)(Ab + aOff[m]);
      xl[m] = *(const half8*)(Ab + 4096 + aOff[m]);
    }
#pragma unroll
    for (int n = 0; n < 4; ++n) {
      wh[n] = *(const half8*)(Bb + bOff[n]);
      wl[n] = *(const half8*)(Bb + 16384 + bOff[n]);
    }
#pragma unroll
    for (int m = 0; m < 2; ++m)
#pragma unroll
      for (int n = 0; n < 4; ++n) {
        acc[m][n] = __builtin_amdgcn_mfma_f32_16x16x32_f16(xh[m], wh[n], acc[m][n], 0, 0, 0);
        f32x4 c = accc[m][n];
        c = __builtin_amdgcn_mfma_f32_16x16x32_f16(xh[m], wl[n], c, 0, 0, 0);
        c = __builtin_amdgcn_mfma_f32_16x16x32_f16(xl[m], wh[n], c, 0, 0, 0);
        accc[m][n] = c;
      }

    if (t + 1 < KSTEPS) {
      write_x(nxt, xcons);  // compiler emits counted vmcnt for xcons's load
      // drain my W(t+1) staging loads (X(t+2) stays in flight), then barrier
      if (t + 2 < KSTEPS) {
        asm volatile("s_waitcnt vmcnt(1)" ::: "memory");
      } else {
        asm volatile("s_waitcnt vmcnt(0)" ::: "memory");
      }
      asm volatile("s_waitcnt lgkmcnt(0)" ::: "memory");
      __builtin_amdgcn_s_barrier();
    }
  };

  // prologue: W(0) staged+drained, A(0) written, X(1) in flight
  float4 xqA, xqB;
  stage_w(0, 0);
  load_x(0, xqA);
  write_x(0, xqA);   // auto-wait drains W(0) too (issued before X(0))
  load_x(1, xqB);    // issued after write_x's wait -> stays in flight
  __syncthreads();

#pragma clang loop unroll(disable)
  for (int t = 0; t < KSTEPS; t += 2) {
    body(t, xqA, xqB);      // consumes X(t+1)=xqB, loads X(t+2)->xqA
    body(t + 1, xqB, xqA);  // consumes X(t+2)=xqA, loads X(t+3)->xqB
  }
  __syncthreads();

  // ---- epilogue: sigmoid -> LDS scores [64][260] f32 (padded)
  float* sc = (float*)smem;
#pragma unroll
  for (int m = 0; m < 2; ++m)
#pragma unroll
    for (int n = 0; n < 4; ++n)
#pragma unroll
      for (int r = 0; r < 4; ++r) {
        int row = wm * 32 + m * 16 + lg * 4 + r;
        int col = wn * 64 + n * 16 + lr;
        float v = (acc[m][n][r] + accc[m][n][r]) * DESCALE;
        sc[row * 260 + col] = 1.0f / (1.0f + expf(-v));
      }
  __syncthreads();

  // ---- fused top-8: exact lax.top_k semantics via packed (key, 255-idx) u64
  const float bb0 = bias[lane];
  const float bb1 = bias[lane + 64];
  const float bb2 = bias[lane + 128];
  const float bb3 = bias[lane + 192];
  const size_t TOT = (size_t)M_TOK * TOPK;

  for (int i = 0; i < 8; ++i) {
    int row = wid * 8 + i;
    float s0 = sc[row * 260 + lane];
    float s1 = sc[row * 260 + lane + 64];
    float s2 = sc[row * 260 + lane + 128];
    float s3 = sc[row * 260 + lane + 192];
    unsigned long long c0 = pack_ci(s0 + bb0, lane);
    unsigned long long c1 = pack_ci(s1 + bb1, lane + 64);
    unsigned long long c2 = pack_ci(s2 + bb2, lane + 128);
    unsigned long long c3 = pack_ci(s3 + bb3, lane + 192);
    float ssum = 0.f, my_s = 0.f;
    int my_idx = 0;
#pragma unroll
    for (int p = 0; p < TOPK; ++p) {
      unsigned long long b01 = c0 > c1 ? c0 : c1;
      unsigned long long b23 = c2 > c3 ? c2 : c3;
      unsigned long long best = b01 > b23 ? b01 : b23;
#pragma unroll
      for (int off = 1; off < 64; off <<= 1) {
        unsigned long long o = shflx64(best, off);
        if (o > best) best = o;
      }
      int idxw = 255 - (int)(best & 0xffull);
      int lw = idxw & 63;
      int jw = idxw >> 6;  // wave-uniform
      float sel = jw == 0 ? s0 : jw == 1 ? s1 : jw == 2 ? s2 : s3;
      float sw = __shfl(sel, lw);
      ssum += sw;
      if (lane == p) { my_idx = idxw; my_s = sw; }
      if (lane == lw) {
        if (jw == 0) c0 = 0ull;
        else if (jw == 1) c1 = 0ull;
        else if (jw == 2) c2 = 0ull;
        else c3 = 0ull;
      }
    }
    if (lane < TOPK) {
      size_t rg = (size_t)(m0 + row);
      out[rg * TOPK + lane] = (float)my_idx;                          // indices
      out[TOT + rg * TOPK + lane] = my_s * (2.5f / (ssum + 1e-20f));  // weights
    }
  }
}

extern "C" void kernel_launch(void* const* d_in, const int* in_sizes, int n_in,
                              void* d_out, int out_size, void* d_ws, size_t ws_size,
                              hipStream_t stream) {
  const float* X = (const float*)d_in[0];
  const float* W = (const float*)d_in[1];
  const float* bias = (const float*)d_in[2];
  float* out = (float*)d_out;

  const size_t wneed = (size_t)KSTEPS * WTILE;  // 7.34 MB
  if (d_ws != nullptr && ws_size >= wneed) {
    prep_w_kernel<<<KSTEPS, 256, 0, stream>>>(W, (unsigned char*)d_ws);
    gate_kernel<true><<<M_TOK / BM, 512, 0, stream>>>(
        X, W, (const unsigned char*)d_ws, bias, out);
  } else {
    gate_kernel<false><<<M_TOK / BM, 512, 0, stream>>>(X, W, nullptr, bias, out);
  }
}